// Round 10
// baseline (105.839 us; speedup 1.0000x reference)
//
#include <hip/hip_runtime.h>
#include <stdint.h>

typedef _Float16 half8 __attribute__((ext_vector_type(8)));
typedef float f32x16 __attribute__((ext_vector_type(16)));

// ---------------- layout ----------------
// th2 (ws): 36 blobs (p = i*12 + j*4 + oct) of 18432 B, K-MAJOR:
//   16B unit u = off*64 + f (off 0..17, f 0..63), halves h 0..7:
//   k_local = off*8 + h (0..143), kk = oct*144 + k_local, c = kk/18, m = kk%18
//   value: m<17 ? wspl*cp[m] : wsil  for theta[i][f][j,c,m].
//   Linear blob == linear LDS image => global_load_lds, zero staging regs.
// LDS (k-major): A addr = off*512 + px*16 (+h*2) ; B addr = off*1024 + f*16.
//   Fragment reads (lane: off = kh+2s fixed, px/f = r31 consecutive) are 32
//   CONSECUTIVE 16B units per wave => bank-conflict-free BY CONSTRUCTION
//   (R9's stride-class tuning gave 1.33M conflicts = +2cy per b128 read).
#define NBH (36 * 9216)              // th2 halves = 331776
#define PREP_BLOCKS (NBH / 256)      // 1296 exactly

__global__ __launch_bounds__(256) void kan_prep(
    const float* __restrict__ cp, const float* __restrict__ wspl,
    const float* __restrict__ wsil, _Float16* __restrict__ th2)
{
    int e = blockIdx.x * 256 + threadIdx.x;    // < NBH exactly
    int p = e / 9216;
    int r = e - p * 9216;
    int u = r >> 3, h = r & 7;
    int off = u >> 6, f = u & 63;
    int i = p / 12;
    int rr = p - i * 12;
    int j = rr >> 2, oct = rr & 3;
    int kk = oct * 144 + off * 8 + h;
    int c = kk / 18;
    int m = kk - c * 18;
    int base = ((f * 32 + c) * 3 + i) * 3 + j;           // (F,C,3,3) flat
    float v = (m < 17) ? wspl[base] * cp[base * 17 + m] : wsil[base];
    th2[e] = (_Float16)v;
}

// Fused GEMM, atomic-free. Block = 128 thr = 2 waves; tile 32px x 64f;
// grid 512 = 2 blocks/output-row = 2 blocks/CU (45 KB LDS each) -- the two
// co-resident blocks are unsynchronized and hide each other's stalls.
// K = 5184 in 36 chunks of 144 (p -> i=p/12, j, oct). K-PARITY SPLIT:
// wave w does s = w, w+2, ... (2 acc tiles, A-frag read once per 2 MFMA ->
// 3 reads / 2 MFMA, -25% LDS reads); partials summed via LDS at the end.
// Pipeline: B dbuf, phase p issues {x(p+1), STAGE(p+1)} then waits
// vmcnt(10) -- exactly those 10 stay in flight across BOTH barriers.
__global__ __launch_bounds__(128) void kan_main(
    const float* __restrict__ x, const _Float16* __restrict__ th2,
    const float* __restrict__ bias, float* __restrict__ out)
{
    __shared__ __align__(16) _Float16 lA[32 * 144];      // 9216 B
    __shared__ __align__(16) _Float16 lB[2][64 * 144];   // 2 x 18432 B

    const int bx = blockIdx.x;                     // (b*64+ho)*2 + ph
    const int ph = bx & 1;
    const int row = bx >> 1;
    const int b = row >> 6;
    const int ho = row & 63;

    const int tid = threadIdx.x;                   // 0..127
    const int wv = tid >> 6;                       // wave = k-parity
    const int lane = tid & 63;
    const int r31 = lane & 31;
    const int kh = lane >> 5;
    const int apx = tid >> 2;                      // A px row 0..31
    const int cc = tid & 3;                        // c-pair index

    const char* thB = (const char*)th2;

    const float bv0 = bias[r31];
    const float bv1 = bias[32 + r31];

    // stage blob bi (18432 B) into LDS buffer: 9 insts/wave, 1 KB units
#define STAGE(dst, bi)                                                         \
    {                                                                          \
        const char* gs_ = thB + (size_t)(bi) * 18432 + lane * 16;              \
        char* ld_ = (char*)(dst);                                              \
        _Pragma("unroll")                                                      \
        for (int t_ = 0; t_ < 9; ++t_) {                                       \
            int o_ = (t_ * 2 + wv) << 10;                                      \
            __builtin_amdgcn_global_load_lds(                                  \
                (const __attribute__((address_space(1))) void*)(gs_ + o_),     \
                (__attribute__((address_space(3))) void*)(ld_ + o_),           \
                16, 0, 0);                                                     \
        }                                                                      \
    }

    // x float2 (channels cc*2, cc*2+1) for phase n
    auto xaddr = [&](int n) -> const float2* {
        int i_ = n / 12;
        int rr_ = n - i_ * 12;
        int j_ = rr_ >> 2, oct_ = rr_ & 3;
        return (const float2*)(
            x + ((size_t)((b * 66 + ho + i_) * 66 + ph * 32 + apx + j_)) * 32
              + oct_ * 8 + cc * 2);
    };

    float2 xc = *xaddr(0);
    __builtin_amdgcn_sched_barrier(0);
    STAGE(lB[0], 0)
    __builtin_amdgcn_sched_barrier(0);

    f32x16 acc0, acc1;
#pragma unroll
    for (int r = 0; r < 16; ++r) { acc0[r] = 0.0f; acc1[r] = 0.0f; }

    int cur = 0;
    for (int p = 0; p < 36; ++p) {
        float2 xn = xc;
        if (p < 35) {
            xn = *xaddr(p + 1);                    // 1 vmem
            __builtin_amdgcn_sched_barrier(0);
            STAGE(lB[cur ^ 1], p + 1)              // 9 vmem
            __builtin_amdgcn_sched_barrier(0);
        }
        // ---- A-build (uses xc from last phase: its implicit wait drains
        //      only loads OLDER than this phase's 10 -- pipeline preserved)
        {
            union { _Float16 h[36]; uint64_t q[9]; } pk;
#pragma unroll
            for (int d = 0; d < 2; ++d) {
                float pv = (d == 0) ? xc.x : xc.y;
                float u = fmaf(fminf(1.0f, fmaxf(-1.0f, pv)), 8.0f, 8.0f);
#pragma unroll
                for (int m = 0; m < 17; ++m)
                    pk.h[d * 18 + m] =
                        (_Float16)fmaxf(0.0f, 1.0f - fabsf(u - (float)m));
                pk.h[d * 18 + 17] = (_Float16)(
                    pv * __builtin_amdgcn_rcpf(1.0f + __expf(-pv)));
            }
#pragma unroll
            for (int t = 0; t < 9; ++t) {          // k-major scatter, b64
                int w = 9 * cc + t;
                *(uint64_t*)((char*)lA + ((w >> 1) << 9) + apx * 16
                             + ((w & 1) << 3)) = pk.q[t];
            }
        }
        // ---- counted drain: blob p (9 oldest) done; keep {x(p+1), blob p+1}
        if (p < 35) asm volatile("s_waitcnt vmcnt(10) lgkmcnt(0)" ::: "memory");
        else        asm volatile("s_waitcnt vmcnt(0) lgkmcnt(0)" ::: "memory");
        __builtin_amdgcn_s_barrier();
        __builtin_amdgcn_sched_barrier(0);

        // ---- k-parity MFMA: wave wv takes s = wv, wv+2, ...
        {
            const char* pbase = (const char*)lB[cur];
            for (int s = wv; s < 9; s += 2) {
                const char* pa = (const char*)lA + ((kh + 2 * s) << 9) + r31 * 16;
                const char* pb = pbase + ((kh + 2 * s) << 10) + r31 * 16;
                half8 a  = *(const half8*)pa;
                half8 g0 = *(const half8*)pb;
                half8 g1 = *(const half8*)(pb + 512);
                acc0 = __builtin_amdgcn_mfma_f32_32x32x16_f16(a, g0, acc0, 0, 0, 0);
                acc1 = __builtin_amdgcn_mfma_f32_32x32x16_f16(a, g1, acc1, 0, 0, 0);
            }
        }
        asm volatile("s_waitcnt lgkmcnt(0)" ::: "memory");  // reads retired
        __builtin_amdgcn_s_barrier();
        cur ^= 1;
        xc = xn;
    }
#undef STAGE

    // ---- cross-wave k-reduction + store.
    // C/D layout (verified): col = lane&31, row = (reg&3)+8*(reg>>2)+4*(lane>>5)
    float* red = (float*)lB;                       // 8 KB scratch
    if (wv == 1) {
#pragma unroll
        for (int r = 0; r < 16; ++r) {
            int rowD = (r & 3) + 8 * (r >> 2) + 4 * kh;
            red[rowD * 64 + r31]      = acc0[r];
            red[rowD * 64 + 32 + r31] = acc1[r];
        }
    }
    __syncthreads();
    if (wv == 0) {
        float* obase = out + ((size_t)((b * 64 + ho) * 64 + ph * 32)) * 64;
#pragma unroll
        for (int r = 0; r < 16; ++r) {
            int rowD = (r & 3) + 8 * (r >> 2) + 4 * kh;
            obase[(size_t)rowD * 64 + r31] =
                acc0[r] + red[rowD * 64 + r31] + bv0;
            obase[(size_t)rowD * 64 + 32 + r31] =
                acc1[r] + red[rowD * 64 + 32 + r31] + bv1;
        }
    }
}

extern "C" void kernel_launch(void* const* d_in, const int* in_sizes, int n_in,
                              void* d_out, int out_size, void* d_ws, size_t ws_size,
                              hipStream_t stream) {
    const float* x    = (const float*)d_in[0];
    const float* cp   = (const float*)d_in[1];
    const float* wspl = (const float*)d_in[2];
    const float* wsil = (const float*)d_in[3];
    const float* bias = (const float*)d_in[4];
    float* out = (float*)d_out;

    _Float16* th2 = (_Float16*)d_ws;

    kan_prep<<<PREP_BLOCKS, 256, 0, stream>>>(cp, wspl, wsil, th2);
    kan_main<<<512, 128, 0, stream>>>(x, th2, bias, out);
}

// Round 11
// 105.769 us; speedup vs baseline: 1.0007x; 1.0007x over previous
//
#include <hip/hip_runtime.h>
#include <stdint.h>

typedef _Float16 half8 __attribute__((ext_vector_type(8)));
typedef float f32x16 __attribute__((ext_vector_type(16)));

// ---------------- layout ----------------
// th2 (ws): 36 blobs (p = i*12 + j*4 + oct) of 18432 B, K-MAJOR (R10-verified):
//   16B unit u = off*64 + f (off 0..17, f 0..63), halves h 0..7:
//   k_local = off*8 + h, kk = oct*144 + k_local, c = kk/18, m = kk%18;
//   value: m<17 ? wspl*cp[m] : wsil  for theta[i][f][j,c,m].
//   B-frag for (s,kh): 16B at off = 2s+kh, f = lane&31 (+32) -> 32 lanes read
//   CONSECUTIVE units: coalesced global loads, L1/L2-hot (648 KB total).
// xt (ws): x transposed to [b][c][h][w] so per-(c) loads are lane-coalesced.
// A-frag: synthesized IN REGISTERS. 144 % 18 == 0 => per (s,h) the pair
//   (m, c_local) is compile-time; lane kh-dependence handled by 2-way
//   cndmask on compile-time-indexed u[]/si[]. No LDS, no barriers anywhere.
#define NTH2H 331776
#define NXT   557568
#define XT_OFF 663552                       // bytes = NTH2H*2
#define PREP_BLOCKS ((NTH2H + NXT) / 256)   // 3474 exactly

__global__ __launch_bounds__(256) void kan_prep(
    const float* __restrict__ x, const float* __restrict__ cp,
    const float* __restrict__ wspl, const float* __restrict__ wsil,
    _Float16* __restrict__ th2, float* __restrict__ xt)
{
    int tid = blockIdx.x * 256 + threadIdx.x;
    if (tid < NTH2H) {                      // th2 k-major blobs (R10-verified)
        int e = tid;
        int p = e / 9216;
        int r = e - p * 9216;
        int u = r >> 3, h = r & 7;
        int off = u >> 6, f = u & 63;
        int i = p / 12;
        int rr = p - i * 12;
        int j = rr >> 2, oct = rr & 3;
        int kk = oct * 144 + off * 8 + h;
        int c = kk / 18;
        int m = kk - c * 18;
        int base = ((f * 32 + c) * 3 + i) * 3 + j;       // (F,C,3,3) flat
        float v = (m < 17) ? wspl[base] * cp[base * 17 + m] : wsil[base];
        th2[e] = (_Float16)v;
    } else {                                // x transpose -> [b][c][66][66]
        int e2 = tid - NTH2H;
        int w  = e2 % 66;
        int t1 = e2 / 66;
        int h  = t1 % 66;
        int t2 = t1 / 66;
        int c  = t2 & 31;
        int b  = t2 >> 5;
        xt[e2] = x[((size_t)((b * 66 + h) * 66 + w)) * 32 + c];
    }
}

// Fused GEMM, LDS-FREE + BARRIER-FREE. 2048 blocks x 64 thr = 2048
// independent waves = 8 free-running waves/CU (R2..R10: every barrier-locked
// LDS structure pinned at 40-45us with all pipes <25% busy).
// Wave = (kp 0..3, row 0..255, ph 0..1): 32px x 64f tile, phases
// p = kp*9 + q (9 of 36, disjoint K) -> no A-build duplication; atomicAdd
// epilogue (R2-measured: no write blowup), kp==0 carries bias, out memset.
__global__ __launch_bounds__(64) void kan_main(
    const float* __restrict__ xt, const _Float16* __restrict__ th2,
    const float* __restrict__ bias, float* __restrict__ out)
{
    const int bid = blockIdx.x;             // kp*512 + row*2 + ph
    const int kp  = bid >> 9;
    const int rp  = bid & 511;
    const int ph  = rp & 1;
    const int row = rp >> 1;
    const int b   = row >> 6;
    const int ho  = row & 63;

    const int lane = threadIdx.x;
    const int r31  = lane & 31;
    const int kh   = lane >> 5;

    f32x16 acc0, acc1;
    {
        float b0 = (kp == 0) ? bias[r31] : 0.0f;
        float b1 = (kp == 0) ? bias[32 + r31] : 0.0f;
#pragma unroll
        for (int r = 0; r < 16; ++r) { acc0[r] = b0; acc1[r] = b1; }
    }

    // xt element for (c, i, j): xtb[c*4356 + i*66 + j]
    const float* xtb = xt + (size_t)((b * 32) * 66 + ho) * 66 + ph * 32 + r31;
    // B-frag base: + p*18432 + s*2048 (+512 for f-half 1)
    const char* thb = (const char*)th2 + (kh << 10) + r31 * 16;

    // per-s constants: k0 = 16s (kh=0) / 16s+8 (kh=1); r0 = k0%18, c = k0/18
    constexpr int R0A[9] = {0, 16, 14, 12, 10, 8, 6, 4, 2};
    constexpr int R0B[9] = {8, 6, 4, 2, 0, 16, 14, 12, 10};
    constexpr int CA_[9] = {0, 0, 1, 2, 3, 4, 5, 6, 7};
    constexpr int CB_[9] = {0, 1, 2, 3, 4, 4, 5, 6, 7};

    const bool hb = (kh != 0);

#pragma unroll 1
    for (int q = 0; q < 9; ++q) {
        const int p   = kp * 9 + q;
        const int i   = p / 12;
        const int rr  = p - i * 12;
        const int j   = rr >> 2;
        const int oct = rr & 3;

        const char* tb = thb + (size_t)p * 18432;

        // ---- per-phase channel features (8 c's), compile-time indexed
        float u[8], si[8];
#pragma unroll
        for (int cl = 0; cl < 8; ++cl) {
            float xv = xtb[(oct * 8 + cl) * 4356 + i * 66 + j];
            u[cl]  = fmaf(fminf(1.0f, fmaxf(-1.0f, xv)), 8.0f, 8.0f);
            si[cl] = xv * __builtin_amdgcn_rcpf(1.0f + __expf(-xv));
        }

#pragma unroll
        for (int s = 0; s < 9; ++s) {
            half8 b0 = *(const half8*)(tb + s * 2048);
            half8 b1 = *(const half8*)(tb + s * 2048 + 512);

            const int ca  = CA_[s], cb = CB_[s];
            const int ca1 = (ca < 7) ? ca + 1 : 7;
            const int cb1 = (cb < 7) ? cb + 1 : 7;
            const int r0i = hb ? R0B[s] : R0A[s];
            const float r0f = (float)r0i;
            const float ta  = (hb ? u[cb] : u[ca]) - r0f;          // pre-wrap
            const float tbv = (hb ? u[cb1] : u[ca1]) - r0f + 18.0f; // post-wrap
            const float sv  = hb ? si[cb] : si[ca];                 // silu slot

            half8 a;
#pragma unroll
            for (int h = 0; h < 8; ++h) {
                const bool pre = (r0i + h) < 18;          // m = r0+h (-18)
                float e   = (pre ? ta : tbv) - (float)h;
                float hat = fmaxf(0.0f, 1.0f - fabsf(e));
                float val = (r0i == 17 - h) ? sv : hat;   // m==17 -> silu
                a[h] = (_Float16)val;
            }
            acc0 = __builtin_amdgcn_mfma_f32_32x32x16_f16(a, b0, acc0, 0, 0, 0);
            acc1 = __builtin_amdgcn_mfma_f32_32x32x16_f16(a, b1, acc1, 0, 0, 0);
        }
    }

    // C/D layout (verified): col = lane&31, row = (reg&3)+8*(reg>>2)+4*(lane>>5)
    float* obase = out + ((size_t)((b * 64 + ho) * 64 + ph * 32)) * 64;
#pragma unroll
    for (int r = 0; r < 16; ++r) {
        int rowD = (r & 3) + 8 * (r >> 2) + 4 * kh;
        atomicAdd(obase + (size_t)rowD * 64 + r31,      acc0[r]);
        atomicAdd(obase + (size_t)rowD * 64 + 32 + r31, acc1[r]);
    }
}

extern "C" void kernel_launch(void* const* d_in, const int* in_sizes, int n_in,
                              void* d_out, int out_size, void* d_ws, size_t ws_size,
                              hipStream_t stream) {
    const float* x    = (const float*)d_in[0];
    const float* cp   = (const float*)d_in[1];
    const float* wspl = (const float*)d_in[2];
    const float* wsil = (const float*)d_in[3];
    const float* bias = (const float*)d_in[4];
    float* out = (float*)d_out;

    uint8_t* ws = (uint8_t*)d_ws;
    _Float16* th2 = (_Float16*)ws;
    float* xt = (float*)(ws + XT_OFF);

    kan_prep<<<PREP_BLOCKS, 256, 0, stream>>>(x, cp, wspl, wsil, th2, xt);
    hipMemsetAsync(d_out, 0, (size_t)out_size * 4, stream);

    kan_main<<<2048, 64, 0, stream>>>(xt, th2, bias, out);
}

// Round 12
// 90.316 us; speedup vs baseline: 1.1719x; 1.1711x over previous
//
#include <hip/hip_runtime.h>
#include <stdint.h>

typedef _Float16 half8 __attribute__((ext_vector_type(8)));
typedef float f32x16 __attribute__((ext_vector_type(16)));

// ---------------- layout ----------------
// th2 (ws): 36 blobs (p = i*12 + j*4 + oct) of 18432 B, K-MAJOR (R10/R11-
//   verified): 16B unit u = off*64 + f (off 0..17, f 0..63), halves h 0..7:
//   k_local = off*8 + h, kk = oct*144 + k_local, c = kk/18, m = kk%18;
//   value: m<17 ? wspl*cp[m] : wsil  for theta[i][f][j,c,m].
//   B-frag for (s,kh): 16B at off = 2s+kh, f = lane&31 (+32) -> 32 lanes read
//   CONSECUTIVE units: coalesced global loads, L1/L2-hot (648 KB total).
// xt (ws): x transposed to [b][c][h][w] so per-(c) loads are lane-coalesced.
// A-frag: synthesized IN REGISTERS (R11-verified): 144 % 18 == 0 => per
//   (s,h) the (m, c_local) pair is compile-time; kh handled by 2-way selects.
// R12 delta vs R11: 4 kp-waves live in ONE 256-thr block; end-of-kernel LDS
//   reduction + single store => NO atomics, NO memset. (R11's 4 MB memset
//   was starved to 41.76 us by the concurrent 256 MiB poison fill -- ord 310:
//   41.76 us, ~zero HBM bytes -- and re-serialized main behind the fills.
//   R8 proved kernels can slide under the fill window: total 88.4.)
#define NTH2H 331776
#define NXT   557568
#define XT_OFF 663552                       // bytes = NTH2H*2
#define PREP_BLOCKS ((NTH2H + NXT) / 256)   // 3474 exactly

__global__ __launch_bounds__(256) void kan_prep(
    const float* __restrict__ x, const float* __restrict__ cp,
    const float* __restrict__ wspl, const float* __restrict__ wsil,
    _Float16* __restrict__ th2, float* __restrict__ xt)
{
    int tid = blockIdx.x * 256 + threadIdx.x;
    if (tid < NTH2H) {                      // th2 k-major blobs
        int e = tid;
        int p = e / 9216;
        int r = e - p * 9216;
        int u = r >> 3, h = r & 7;
        int off = u >> 6, f = u & 63;
        int i = p / 12;
        int rr = p - i * 12;
        int j = rr >> 2, oct = rr & 3;
        int kk = oct * 144 + off * 8 + h;
        int c = kk / 18;
        int m = kk - c * 18;
        int base = ((f * 32 + c) * 3 + i) * 3 + j;       // (F,C,3,3) flat
        float v = (m < 17) ? wspl[base] * cp[base * 17 + m] : wsil[base];
        th2[e] = (_Float16)v;
    } else {                                // x transpose -> [b][c][66][66]
        int e2 = tid - NTH2H;
        int w  = e2 % 66;
        int t1 = e2 / 66;
        int h  = t1 % 66;
        int t2 = t1 / 66;
        int c  = t2 & 31;
        int b  = t2 >> 5;
        xt[e2] = x[((size_t)((b * 66 + h) * 66 + w)) * 32 + c];
    }
}

// Fused GEMM, LDS-free main loop, barrier-free until the final reduction.
// Block = 256 thr = 4 waves = kp 0..3 (disjoint K quarters, 9 phases each);
// block owns the 32px x 64f tile (row, ph). Grid 512 -> 2048 waves =
// 8 free-running waves/CU. Epilogue: waves 1-3 dump acc to 24 KB LDS, one
// __syncthreads, wave 0 sums + stores out EXACTLY ONCE (no atomics/memset).
__global__ __launch_bounds__(256) void kan_main(
    const float* __restrict__ xt, const _Float16* __restrict__ th2,
    const float* __restrict__ bias, float* __restrict__ out)
{
    __shared__ float red[3][2048];          // 24 KB reduction scratch

    const int bid = blockIdx.x;             // row*2 + ph
    const int ph  = bid & 1;
    const int row = bid >> 1;
    const int b   = row >> 6;
    const int ho  = row & 63;

    const int tid  = threadIdx.x;
    const int kp   = tid >> 6;              // wave = K quarter
    const int lane = tid & 63;
    const int r31  = lane & 31;
    const int kh   = lane >> 5;

    f32x16 acc0, acc1;
    {
        float b0 = (kp == 0) ? bias[r31] : 0.0f;
        float b1 = (kp == 0) ? bias[32 + r31] : 0.0f;
#pragma unroll
        for (int r = 0; r < 16; ++r) { acc0[r] = b0; acc1[r] = b1; }
    }

    // xt element for (c, i, j): xtb[c*4356 + i*66 + j]
    const float* xtb = xt + (size_t)((b * 32) * 66 + ho) * 66 + ph * 32 + r31;
    // B-frag base: + p*18432 + s*2048 (+512 for f-half 1)
    const char* thb = (const char*)th2 + (kh << 10) + r31 * 16;

    // per-s constants: k0 = 16s (kh=0) / 16s+8 (kh=1); r0 = k0%18, c = k0/18
    constexpr int R0A[9] = {0, 16, 14, 12, 10, 8, 6, 4, 2};
    constexpr int R0B[9] = {8, 6, 4, 2, 0, 16, 14, 12, 10};
    constexpr int CA_[9] = {0, 0, 1, 2, 3, 4, 5, 6, 7};
    constexpr int CB_[9] = {0, 1, 2, 3, 4, 4, 5, 6, 7};

    const bool hb = (kh != 0);

#pragma unroll 1
    for (int q = 0; q < 9; ++q) {
        const int p   = kp * 9 + q;
        const int i   = p / 12;
        const int rr  = p - i * 12;
        const int j   = rr >> 2;
        const int oct = rr & 3;

        const char* tb = thb + (size_t)p * 18432;

        // ---- per-phase channel features (8 c's), compile-time indexed
        float u[8], si[8];
#pragma unroll
        for (int cl = 0; cl < 8; ++cl) {
            float xv = xtb[(oct * 8 + cl) * 4356 + i * 66 + j];
            u[cl]  = fmaf(fminf(1.0f, fmaxf(-1.0f, xv)), 8.0f, 8.0f);
            si[cl] = xv * __builtin_amdgcn_rcpf(1.0f + __expf(-xv));
        }

#pragma unroll
        for (int s = 0; s < 9; ++s) {
            half8 b0 = *(const half8*)(tb + s * 2048);
            half8 b1 = *(const half8*)(tb + s * 2048 + 512);

            const int ca  = CA_[s], cb = CB_[s];
            const int ca1 = (ca < 7) ? ca + 1 : 7;
            const int cb1 = (cb < 7) ? cb + 1 : 7;
            const int r0i = hb ? R0B[s] : R0A[s];
            const float r0f = (float)r0i;
            const float ta  = (hb ? u[cb] : u[ca]) - r0f;           // pre-wrap
            const float tbv = (hb ? u[cb1] : u[ca1]) - r0f + 18.0f; // post-wrap
            const float sv  = hb ? si[cb] : si[ca];                 // silu slot

            half8 a;
#pragma unroll
            for (int h = 0; h < 8; ++h) {
                const bool pre = (r0i + h) < 18;          // m = r0+h (-18)
                float e   = (pre ? ta : tbv) - (float)h;
                float hat = fmaxf(0.0f, 1.0f - fabsf(e));
                float val = (r0i == 17 - h) ? sv : hat;   // m==17 -> silu
                a[h] = (_Float16)val;
            }
            acc0 = __builtin_amdgcn_mfma_f32_32x32x16_f16(a, b0, acc0, 0, 0, 0);
            acc1 = __builtin_amdgcn_mfma_f32_32x32x16_f16(a, b1, acc1, 0, 0, 0);
        }
    }

    // ---- cross-wave K reduction + single store.
    // C/D layout (verified): col = lane&31, row = (reg&3)+8*(reg>>2)+4*(lane>>5)
    if (kp != 0) {
#pragma unroll
        for (int r = 0; r < 16; ++r) {
            int rowD = (r & 3) + 8 * (r >> 2) + 4 * kh;
            red[kp - 1][rowD * 64 + r31]      = acc0[r];
            red[kp - 1][rowD * 64 + 32 + r31] = acc1[r];
        }
    }
    __syncthreads();
    if (kp == 0) {
        float* obase = out + ((size_t)((b * 64 + ho) * 64 + ph * 32)) * 64;
#pragma unroll
        for (int r = 0; r < 16; ++r) {
            int rowD = (r & 3) + 8 * (r >> 2) + 4 * kh;
            int o0 = rowD * 64 + r31, o1 = rowD * 64 + 32 + r31;
            obase[o0] = acc0[r] + red[0][o0] + red[1][o0] + red[2][o0];
            obase[o1] = acc1[r] + red[0][o1] + red[1][o1] + red[2][o1];
        }
    }
}

extern "C" void kernel_launch(void* const* d_in, const int* in_sizes, int n_in,
                              void* d_out, int out_size, void* d_ws, size_t ws_size,
                              hipStream_t stream) {
    const float* x    = (const float*)d_in[0];
    const float* cp   = (const float*)d_in[1];
    const float* wspl = (const float*)d_in[2];
    const float* wsil = (const float*)d_in[3];
    const float* bias = (const float*)d_in[4];
    float* out = (float*)d_out;

    uint8_t* ws = (uint8_t*)d_ws;
    _Float16* th2 = (_Float16*)ws;
    float* xt = (float*)(ws + XT_OFF);

    kan_prep<<<PREP_BLOCKS, 256, 0, stream>>>(x, cp, wspl, wsil, th2, xt);
    kan_main<<<512, 256, 0, stream>>>(xt, th2, bias, out);
}